// Round 6
// baseline (770.156 us; speedup 1.0000x reference)
//
#include <hip/hip_runtime.h>
#include <cstdio>

typedef unsigned short u16;
typedef u16 u16x4 __attribute__((ext_vector_type(4)));
typedef u16 u16x8 __attribute__((ext_vector_type(8)));
typedef __bf16 bf16x8 __attribute__((ext_vector_type(8)));
typedef float f32x4 __attribute__((ext_vector_type(4)));

#define AS1 __attribute__((address_space(1)))
#define AS3 __attribute__((address_space(3)))

#define GLOAD16(gsrc, ldst) __builtin_amdgcn_global_load_lds( \
    (const AS1 void*)(gsrc), (AS3 void*)(ldst), 16, 0, 0)

__device__ __forceinline__ u16 f2bf(float f) {
  unsigned u = __builtin_bit_cast(unsigned, f);
  u += 0x7fffu + ((u >> 16) & 1u);
  return (u16)(u >> 16);
}
__device__ __forceinline__ float bf2f(u16 h) {
  return __builtin_bit_cast(float, (unsigned)h << 16);
}

// ---------------- fp32 -> bf16 convert (with trailing-row zero pad) ----------
__global__ __launch_bounds__(256) void cvt_pad_k(const float* __restrict__ src,
                                                 u16* __restrict__ dst,
                                                 long srcN, long dstN) {
  long i = ((long)blockIdx.x * 256 + threadIdx.x) * 8;
  const long stride = (long)gridDim.x * 256 * 8;
  for (; i < dstN; i += stride) {
    u16x8 o = {0,0,0,0,0,0,0,0};
    if (i < srcN) {
      const float4* p = (const float4*)(src + i);
      float4 a = p[0], b = p[1];
      o[0]=f2bf(a.x); o[1]=f2bf(a.y); o[2]=f2bf(a.z); o[3]=f2bf(a.w);
      o[4]=f2bf(b.x); o[5]=f2bf(b.y); o[6]=f2bf(b.z); o[7]=f2bf(b.w);
    }
    *(u16x8*)(dst + i) = o;
  }
}

// ---------------- RMSNorm over last dim (bf16 in/out, fp32 math) -------------
__global__ __launch_bounds__(256) void rms_k(const u16* __restrict__ src, u16* __restrict__ dst,
                                             const float* __restrict__ w,
                                             int sstride, int dstride, int cols) {
  const int row = blockIdx.x;
  const int tid = threadIdx.x;
  const int nch = cols >> 3;
  float x[8];
  float ss = 0.f;
  if (tid < nch) {
    u16x8 v = *(const u16x8*)(src + (size_t)row * sstride + tid * 8);
#pragma unroll
    for (int j = 0; j < 8; ++j) { x[j] = bf2f(v[j]); ss += x[j] * x[j]; }
  } else {
#pragma unroll
    for (int j = 0; j < 8; ++j) x[j] = 0.f;
  }
#pragma unroll
  for (int off = 1; off < 64; off <<= 1) ss += __shfl_xor(ss, off);
  __shared__ float red[4];
  const int wv = tid >> 6, ln = tid & 63;
  if (ln == 0) red[wv] = ss;
  __syncthreads();
  const float tot = red[0] + red[1] + red[2] + red[3];
  const float rs = 1.0f / sqrtf(tot / (float)cols + 1e-6f);
  if (tid < nch) {
    u16x8 o;
#pragma unroll
    for (int j = 0; j < 8; ++j) o[j] = f2bf(x[j] * rs * w[tid * 8 + j]);
    *(u16x8*)(dst + (size_t)row * dstride + tid * 8) = o;
  }
}

// ---------------- RoPE: q_pe (in place, 16 heads) + k_pe -> kpe --------------
// 4 waves/block; each wave handles 4 heads; wave 0 also writes kpe.
__global__ __launch_bounds__(256) void rope_k(u16* __restrict__ q, const u16* __restrict__ kva,
                                              u16* __restrict__ kpe, const int* __restrict__ pos) {
  const int tok = blockIdx.x;          // 0..4095
  const int j = threadIdx.x & 63;
  const int w = threadIdx.x >> 6;
  const float p = (float)pos[tok];
  const int jj = j & 31;
  const float inv = __powf(10000.0f, -(float)jj * (1.0f / 32.0f));
  float s, c;
  __sincosf(p * inv, &s, &c);
  const float sgn = (j < 32) ? -1.0f : 1.0f;
  const int partner = (j < 32) ? j + 32 : j - 32;
  if (w == 0) {
    const float x  = bf2f(kva[(size_t)tok * 640 + 512 + j]);
    const float xp = bf2f(kva[(size_t)tok * 640 + 512 + partner]);
    kpe[(size_t)tok * 64 + j] = f2bf(x * c + sgn * xp * s);
  }
#pragma unroll
  for (int hh = 0; hh < 4; ++hh) {
    const int h = w * 4 + hh;
    const size_t base = (size_t)tok * 3072 + h * 192 + 128;
    const float x  = bf2f(q[base + j]);
    const float xp = bf2f(q[base + partner]);
    q[base + j] = f2bf(x * c + sgn * xp * s);
  }
}

// ---------------- bf16 GEMM: C[M,N] = A[M,K] * B[N,K]^T ----------------------
__global__ __launch_bounds__(256) void gemm_bt(const u16* __restrict__ A, const u16* __restrict__ B,
                                               u16* __restrict__ Cb, float* __restrict__ Cf,
                                               int M, int N, int K) {
  __shared__ __attribute__((aligned(16))) u16 As[128 * 64];
  __shared__ __attribute__((aligned(16))) u16 Bs[128 * 64];
  const int tid = threadIdx.x;
  const int m0 = blockIdx.y * 128, n0 = blockIdx.x * 128;
  const int w = tid >> 6, lane = tid & 63;
  const int wr = w >> 1, wc = w & 1;
  const int lr = lane & 15, g = lane >> 4;

  f32x4 acc[4][4] = {};

  for (int k0 = 0; k0 < K; k0 += 64) {
#pragma unroll
    for (int i = 0; i < 4; ++i) {
      const int c = i * 256 + tid;
      const int row = c >> 3, col = (c & 7) << 3;
      GLOAD16(A + (size_t)(m0 + row) * K + k0 + col, &As[c * 8]);
    }
#pragma unroll
    for (int i = 0; i < 4; ++i) {
      const int c = i * 256 + tid;
      const int row = c >> 3, col = (c & 7) << 3;
      GLOAD16(B + (size_t)(n0 + row) * K + k0 + col, &Bs[c * 8]);
    }
    __syncthreads();
    bf16x8 af[4][2], bfr[4][2];
#pragma unroll
    for (int x = 0; x < 4; ++x)
#pragma unroll
      for (int kk = 0; kk < 2; ++kk) {
        af[x][kk]  = *(const bf16x8*)(&As[(wr * 64 + x * 16 + lr) * 64 + kk * 32 + g * 8]);
        bfr[x][kk] = *(const bf16x8*)(&Bs[(wc * 64 + x * 16 + lr) * 64 + kk * 32 + g * 8]);
      }
#pragma unroll
    for (int mi = 0; mi < 4; ++mi)
#pragma unroll
      for (int ni = 0; ni < 4; ++ni)
#pragma unroll
        for (int kk = 0; kk < 2; ++kk)
          acc[mi][ni] = __builtin_amdgcn_mfma_f32_16x16x32_bf16(af[mi][kk], bfr[ni][kk],
                                                                acc[mi][ni], 0, 0, 0);
    __syncthreads();
  }

  const int rb = m0 + wr * 64, cb = n0 + wc * 64;
#pragma unroll
  for (int mi = 0; mi < 4; ++mi)
#pragma unroll
    for (int ni = 0; ni < 4; ++ni)
#pragma unroll
      for (int i = 0; i < 4; ++i) {
        const int r = rb + mi * 16 + g * 4 + i;
        const int cI = cb + ni * 16 + lr;
        if (Cf) Cf[(size_t)r * N + cI] = acc[mi][ni][i];
        else    Cb[(size_t)r * N + cI] = f2bf(acc[mi][ni][i]);
      }
}

// ---------------- causal flash attention, per (b,head) -----------------------
// grid (32 bh, 16 q-tiles heavy-first); 4 waves x 32 q-rows. KV tile 64.
// LDS = 40KB: Ps aliases Ks (dead after QK^T) -> 3 blocks/CU (was 2 at 59KB).
// Mid-tile barrier (wave-uniform) orders all waves' Ks reads before Ps writes.
__global__ __launch_bounds__(256, 3) void attn_k(const u16* __restrict__ q, const u16* __restrict__ kvb,
                                                 const u16* __restrict__ kpe, u16* __restrict__ ao) {
  __shared__ __attribute__((aligned(16))) u16 Ks[64 * 192];   // also holds Ps after QK
  __shared__ __attribute__((aligned(16))) u16 Vt[128 * 64];

  const float SCALE = 0.07216878364870323f;  // 192^-0.5
  const int bh = blockIdx.x;
  const int b = bh >> 4, h = bh & 15;
  const int j = 15 - blockIdx.y;             // heavy q-tiles dispatch first
  const int tid = threadIdx.x, w = tid >> 6, lane = tid & 63;
  const int lr = lane & 15, g = lane >> 4;

  const int q0 = j * 128;
  const int qrb = q0 + w * 32;
  u16* Psw = &Ks[w * 2304];                  // per-wave 32x72 slice inside Ks

  bf16x8 qf[2][6];
#pragma unroll
  for (int m = 0; m < 2; ++m)
#pragma unroll
    for (int kd = 0; kd < 6; ++kd)
      qf[m][kd] = *(const bf16x8*)(q + (size_t)(b * 2048 + qrb + m * 16 + lr) * 3072 +
                                   h * 192 + kd * 32 + g * 8);

  float mrow[2][4], lrow[2][4];
  f32x4 o[2][8] = {};
#pragma unroll
  for (int m = 0; m < 2; ++m)
#pragma unroll
    for (int i = 0; i < 4; ++i) { mrow[m][i] = -1e30f; lrow[m][i] = 0.f; }

  const int nt = (q0 >> 6) + 2;
  for (int t = 0; t < nt; ++t) {
    const int k0 = t * 64;
    // stage K tile (64 x 192), swizzled: LDS chunk (row, cl) holds global chunk cl^(row&7)
#pragma unroll
    for (int i = 0; i < 6; ++i) {
      const int c = i * 256 + tid;           // 0..1535
      const int row = c / 24, cl = c - row * 24;
      const int cg = cl ^ (row & 7);
      const u16* src = (cg < 16)
        ? (kvb + (size_t)(b * 2048 + k0 + row) * 4096 + h * 256 + cg * 8)
        : (kpe + (size_t)(b * 2048 + k0 + row) * 64 + (cg - 16) * 8);
      GLOAD16(src, &Ks[c * 8]);
    }
    // stage V transposed, swizzled; 4 k-rows packed per ds_write_b64
    {
      const int kq = tid >> 4;               // 0..15, k base = kq*4
      const int vc = (tid & 15) << 3;        // 0..120
      u16x8 vv[4];
#pragma unroll
      for (int r = 0; r < 4; ++r)
        vv[r] = *(const u16x8*)(kvb + (size_t)(b * 2048 + k0 + kq * 4 + r) * 4096 + h * 256 + 128 + vc);
#pragma unroll
      for (int e = 0; e < 8; ++e) {
        const int v = vc + e;
        const int cx = (kq >> 1) ^ (v & 7) ^ ((v >> 3) & 7);
        u16x4 tq = {vv[0][e], vv[1][e], vv[2][e], vv[3][e]};
        *(u16x4*)(&Vt[v * 64 + cx * 8 + (kq & 1) * 4]) = tq;
      }
    }
    __syncthreads();

    const bool active = (k0 <= qrb + 31);    // wave-uniform
    f32x4 sAcc[2][4] = {};
    if (active) {
      // S = Q K^T (32 rows x 64 keys per wave)
#pragma unroll
      for (int nf = 0; nf < 4; ++nf) {
        const int rr = nf * 16 + lr;
#pragma unroll
        for (int kd = 0; kd < 6; ++kd) {
          const int ch = (kd * 4 + g) ^ (rr & 7);
          const bf16x8 kf = *(const bf16x8*)(&Ks[rr * 192 + ch * 8]);
#pragma unroll
          for (int m = 0; m < 2; ++m)
            sAcc[m][nf] = __builtin_amdgcn_mfma_f32_16x16x32_bf16(qf[m][kd], kf, sAcc[m][nf], 0, 0, 0);
        }
      }
    }
    __syncthreads();                         // all Ks reads done; Ps may overwrite

    if (active) {
      // online softmax over 64 keys
#pragma unroll
      for (int m = 0; m < 2; ++m) {
        float sv[4][4];
#pragma unroll
        for (int nf = 0; nf < 4; ++nf)
#pragma unroll
          for (int i = 0; i < 4; ++i) {
            const int qrow = qrb + m * 16 + g * 4 + i;
            const int kcol = k0 + nf * 16 + lr;
            const float vS = sAcc[m][nf][i] * SCALE;
            sv[nf][i] = (kcol > qrow) ? -1e30f : vS;
          }
        float fac[4], mn[4];
#pragma unroll
        for (int i = 0; i < 4; ++i) {
          float rm = fmaxf(fmaxf(sv[0][i], sv[1][i]), fmaxf(sv[2][i], sv[3][i]));
          rm = fmaxf(rm, __shfl_xor(rm, 1));
          rm = fmaxf(rm, __shfl_xor(rm, 2));
          rm = fmaxf(rm, __shfl_xor(rm, 4));
          rm = fmaxf(rm, __shfl_xor(rm, 8));
          mn[i] = fmaxf(mrow[m][i], rm);
          fac[i] = __expf(mrow[m][i] - mn[i]);
          mrow[m][i] = mn[i];
        }
#pragma unroll
        for (int i = 0; i < 4; ++i) {
          float rsum = 0.f;
#pragma unroll
          for (int nf = 0; nf < 4; ++nf) { sv[nf][i] = __expf(sv[nf][i] - mn[i]); rsum += sv[nf][i]; }
          rsum += __shfl_xor(rsum, 1);
          rsum += __shfl_xor(rsum, 2);
          rsum += __shfl_xor(rsum, 4);
          rsum += __shfl_xor(rsum, 8);
          lrow[m][i] = lrow[m][i] * fac[i] + rsum;
        }
#pragma unroll
        for (int nv = 0; nv < 8; ++nv)
#pragma unroll
          for (int i = 0; i < 4; ++i) o[m][nv][i] *= fac[i];
#pragma unroll
        for (int nf = 0; nf < 4; ++nf)
#pragma unroll
          for (int i = 0; i < 4; ++i)
            Psw[(m * 16 + g * 4 + i) * 72 + nf * 16 + lr] = f2bf(sv[nf][i]);
      }
      asm volatile("s_waitcnt lgkmcnt(0)" ::: "memory");

      // O += P V  (two K=32 sub-steps)
#pragma unroll
      for (int kc = 0; kc < 2; ++kc) {
        bf16x8 vfr[8];
#pragma unroll
        for (int nv = 0; nv < 8; ++nv) {
          const int v = nv * 16 + lr;
          const int cx = (kc * 4 + g) ^ (v & 7) ^ ((v >> 3) & 7);
          vfr[nv] = *(const bf16x8*)(&Vt[v * 64 + cx * 8]);
        }
#pragma unroll
        for (int m = 0; m < 2; ++m) {
          const bf16x8 pf = *(const bf16x8*)(&Psw[(m * 16 + lr) * 72 + kc * 32 + g * 8]);
#pragma unroll
          for (int nv = 0; nv < 8; ++nv)
            o[m][nv] = __builtin_amdgcn_mfma_f32_16x16x32_bf16(pf, vfr[nv], o[m][nv], 0, 0, 0);
        }
      }
    }
    __syncthreads();                         // Ps/Vt reads done before next stage
  }

  // epilogue: normalize and store
#pragma unroll
  for (int m = 0; m < 2; ++m)
#pragma unroll
    for (int i = 0; i < 4; ++i) {
      const float inv = 1.0f / lrow[m][i];
      const size_t tokOff = (size_t)(b * 2048 + qrb + m * 16 + g * 4 + i) * 2048 + h * 128;
#pragma unroll
      for (int nv = 0; nv < 8; ++nv)
        ao[tokOff + nv * 16 + lr] = f2bf(o[m][nv][i] * inv);
    }
}

// -----------------------------------------------------------------------------
extern "C" void kernel_launch(void* const* d_in, const int* in_sizes, int n_in,
                              void* d_out, int out_size, void* d_ws, size_t ws_size,
                              hipStream_t stream) {
  const float* hidden  = (const float*)d_in[0];
  const int*   pos     = (const int*)d_in[1];
  const float* q_a_w   = (const float*)d_in[2];
  const float* q_a_ln  = (const float*)d_in[3];
  const float* q_b_w   = (const float*)d_in[4];
  const float* kv_a_w  = (const float*)d_in[5];
  const float* kv_a_ln = (const float*)d_in[6];
  const float* kv_b_w  = (const float*)d_in[7];
  const float* o_w     = (const float*)d_in[8];
  float* out = (float*)d_out;

  char* ws = (char*)d_ws;
  u16* hb  = (u16*)(ws + 0L);          // 4096x2048
  u16* w1  = (u16*)(ws + 16777216L);   // 1536x2048
  u16* w2  = (u16*)(ws + 23068672L);   // 3072x1536
  u16* w3  = (u16*)(ws + 32505856L);   // 640x2048 (padded)
  u16* w4  = (u16*)(ws + 35127296L);   // 4096x512
  u16* w5  = (u16*)(ws + 39321600L);   // 2048x2048
  u16* qa  = (u16*)(ws + 47710208L);   // 4096x1536
  u16* qb  = (u16*)(ws + 60293120L);   // 4096x3072
  u16* kva = (u16*)(ws + 85458944L);   // 4096x640
  u16* ckv = (u16*)(ws + 90701824L);   // 4096x512
  u16* kpe = (u16*)(ws + 94896128L);   // 4096x64
  u16* kvb = (u16*)(ws + 95420416L);   // 4096x4096
  u16* ao  = (u16*)(ws + 128974848L);  // 4096x2048
  if (ws_size < 145752064UL) { fprintf(stderr, "ws too small: %zu\n", ws_size); return; }

  auto cvt = [&](const float* s, u16* d, long sn, long dn) {
    long blocks = (dn / 8 + 255) / 256; if (blocks > 2048) blocks = 2048;
    cvt_pad_k<<<dim3((unsigned)blocks), dim3(256), 0, stream>>>(s, d, sn, dn);
  };
  cvt(hidden, hb, 4096L * 2048, 4096L * 2048);
  cvt(q_a_w,  w1, 1536L * 2048, 1536L * 2048);
  cvt(q_b_w,  w2, 3072L * 1536, 3072L * 1536);
  cvt(kv_a_w, w3, 576L * 2048,  640L * 2048);
  cvt(kv_b_w, w4, 4096L * 512,  4096L * 512);
  cvt(o_w,    w5, 2048L * 2048, 2048L * 2048);

  gemm_bt<<<dim3(12, 32), 256, 0, stream>>>(hb, w1, qa, nullptr, 4096, 1536, 2048);
  rms_k<<<4096, 256, 0, stream>>>(qa, qa, q_a_ln, 1536, 1536, 1536);
  gemm_bt<<<dim3(24, 32), 256, 0, stream>>>(qa, w2, qb, nullptr, 4096, 3072, 1536);
  gemm_bt<<<dim3(5, 32), 256, 0, stream>>>(hb, w3, kva, nullptr, 4096, 640, 2048);
  rms_k<<<4096, 256, 0, stream>>>(kva, ckv, kv_a_ln, 640, 512, 512);
  rope_k<<<4096, 256, 0, stream>>>(qb, kva, kpe, pos);
  gemm_bt<<<dim3(32, 32), 256, 0, stream>>>(ckv, w4, kvb, nullptr, 4096, 4096, 512);
  attn_k<<<dim3(32, 16), 256, 0, stream>>>(qb, kvb, kpe, ao);
  gemm_bt<<<dim3(16, 32), 256, 0, stream>>>(ao, w5, nullptr, out, 4096, 2048, 2048);
}

// Round 7
// 474.098 us; speedup vs baseline: 1.6245x; 1.6245x over previous
//
#include <hip/hip_runtime.h>
#include <cstdio>

typedef unsigned short u16;
typedef u16 u16x4 __attribute__((ext_vector_type(4)));
typedef u16 u16x8 __attribute__((ext_vector_type(8)));
typedef __bf16 bf16x8 __attribute__((ext_vector_type(8)));
typedef float f32x4 __attribute__((ext_vector_type(4)));

#define AS1 __attribute__((address_space(1)))
#define AS3 __attribute__((address_space(3)))

#define GLOAD16(gsrc, ldst) __builtin_amdgcn_global_load_lds( \
    (const AS1 void*)(gsrc), (AS3 void*)(ldst), 16, 0, 0)

__device__ __forceinline__ u16 f2bf(float f) {
  unsigned u = __builtin_bit_cast(unsigned, f);
  u += 0x7fffu + ((u >> 16) & 1u);
  return (u16)(u >> 16);
}
__device__ __forceinline__ float bf2f(u16 h) {
  return __builtin_bit_cast(float, (unsigned)h << 16);
}

// ---------------- fp32 -> bf16 convert (with trailing-row zero pad) ----------
__global__ __launch_bounds__(256) void cvt_pad_k(const float* __restrict__ src,
                                                 u16* __restrict__ dst,
                                                 long srcN, long dstN) {
  long i = ((long)blockIdx.x * 256 + threadIdx.x) * 8;
  const long stride = (long)gridDim.x * 256 * 8;
  for (; i < dstN; i += stride) {
    u16x8 o = {0,0,0,0,0,0,0,0};
    if (i < srcN) {
      const float4* p = (const float4*)(src + i);
      float4 a = p[0], b = p[1];
      o[0]=f2bf(a.x); o[1]=f2bf(a.y); o[2]=f2bf(a.z); o[3]=f2bf(a.w);
      o[4]=f2bf(b.x); o[5]=f2bf(b.y); o[6]=f2bf(b.z); o[7]=f2bf(b.w);
    }
    *(u16x8*)(dst + i) = o;
  }
}

// ---------------- RMSNorm over last dim (bf16 in/out, fp32 math) -------------
__global__ __launch_bounds__(256) void rms_k(const u16* __restrict__ src, u16* __restrict__ dst,
                                             const float* __restrict__ w,
                                             int sstride, int dstride, int cols) {
  const int row = blockIdx.x;
  const int tid = threadIdx.x;
  const int nch = cols >> 3;
  float x[8];
  float ss = 0.f;
  if (tid < nch) {
    u16x8 v = *(const u16x8*)(src + (size_t)row * sstride + tid * 8);
#pragma unroll
    for (int j = 0; j < 8; ++j) { x[j] = bf2f(v[j]); ss += x[j] * x[j]; }
  } else {
#pragma unroll
    for (int j = 0; j < 8; ++j) x[j] = 0.f;
  }
#pragma unroll
  for (int off = 1; off < 64; off <<= 1) ss += __shfl_xor(ss, off);
  __shared__ float red[4];
  const int wv = tid >> 6, ln = tid & 63;
  if (ln == 0) red[wv] = ss;
  __syncthreads();
  const float tot = red[0] + red[1] + red[2] + red[3];
  const float rs = 1.0f / sqrtf(tot / (float)cols + 1e-6f);
  if (tid < nch) {
    u16x8 o;
#pragma unroll
    for (int j = 0; j < 8; ++j) o[j] = f2bf(x[j] * rs * w[tid * 8 + j]);
    *(u16x8*)(dst + (size_t)row * dstride + tid * 8) = o;
  }
}

// ---------------- RoPE: q_pe (in place, 16 heads) + k_pe -> kpe --------------
// 4 waves/block; each wave handles 4 heads; wave 0 also writes kpe.
__global__ __launch_bounds__(256) void rope_k(u16* __restrict__ q, const u16* __restrict__ kva,
                                              u16* __restrict__ kpe, const int* __restrict__ pos) {
  const int tok = blockIdx.x;          // 0..4095
  const int j = threadIdx.x & 63;
  const int w = threadIdx.x >> 6;
  const float p = (float)pos[tok];
  const int jj = j & 31;
  const float inv = __powf(10000.0f, -(float)jj * (1.0f / 32.0f));
  float s, c;
  __sincosf(p * inv, &s, &c);
  const float sgn = (j < 32) ? -1.0f : 1.0f;
  const int partner = (j < 32) ? j + 32 : j - 32;
  if (w == 0) {
    const float x  = bf2f(kva[(size_t)tok * 640 + 512 + j]);
    const float xp = bf2f(kva[(size_t)tok * 640 + 512 + partner]);
    kpe[(size_t)tok * 64 + j] = f2bf(x * c + sgn * xp * s);
  }
#pragma unroll
  for (int hh = 0; hh < 4; ++hh) {
    const int h = w * 4 + hh;
    const size_t base = (size_t)tok * 3072 + h * 192 + 128;
    const float x  = bf2f(q[base + j]);
    const float xp = bf2f(q[base + partner]);
    q[base + j] = f2bf(x * c + sgn * xp * s);
  }
}

// ---------------- bf16 GEMM: C[M,N] = A[M,K] * B[N,K]^T ----------------------
__global__ __launch_bounds__(256) void gemm_bt(const u16* __restrict__ A, const u16* __restrict__ B,
                                               u16* __restrict__ Cb, float* __restrict__ Cf,
                                               int M, int N, int K) {
  __shared__ __attribute__((aligned(16))) u16 As[128 * 64];
  __shared__ __attribute__((aligned(16))) u16 Bs[128 * 64];
  const int tid = threadIdx.x;
  const int m0 = blockIdx.y * 128, n0 = blockIdx.x * 128;
  const int w = tid >> 6, lane = tid & 63;
  const int wr = w >> 1, wc = w & 1;
  const int lr = lane & 15, g = lane >> 4;

  f32x4 acc[4][4] = {};

  for (int k0 = 0; k0 < K; k0 += 64) {
#pragma unroll
    for (int i = 0; i < 4; ++i) {
      const int c = i * 256 + tid;
      const int row = c >> 3, col = (c & 7) << 3;
      GLOAD16(A + (size_t)(m0 + row) * K + k0 + col, &As[c * 8]);
    }
#pragma unroll
    for (int i = 0; i < 4; ++i) {
      const int c = i * 256 + tid;
      const int row = c >> 3, col = (c & 7) << 3;
      GLOAD16(B + (size_t)(n0 + row) * K + k0 + col, &Bs[c * 8]);
    }
    __syncthreads();
    bf16x8 af[4][2], bfr[4][2];
#pragma unroll
    for (int x = 0; x < 4; ++x)
#pragma unroll
      for (int kk = 0; kk < 2; ++kk) {
        af[x][kk]  = *(const bf16x8*)(&As[(wr * 64 + x * 16 + lr) * 64 + kk * 32 + g * 8]);
        bfr[x][kk] = *(const bf16x8*)(&Bs[(wc * 64 + x * 16 + lr) * 64 + kk * 32 + g * 8]);
      }
#pragma unroll
    for (int mi = 0; mi < 4; ++mi)
#pragma unroll
      for (int ni = 0; ni < 4; ++ni)
#pragma unroll
        for (int kk = 0; kk < 2; ++kk)
          acc[mi][ni] = __builtin_amdgcn_mfma_f32_16x16x32_bf16(af[mi][kk], bfr[ni][kk],
                                                                acc[mi][ni], 0, 0, 0);
    __syncthreads();
  }

  const int rb = m0 + wr * 64, cb = n0 + wc * 64;
#pragma unroll
  for (int mi = 0; mi < 4; ++mi)
#pragma unroll
    for (int ni = 0; ni < 4; ++ni)
#pragma unroll
      for (int i = 0; i < 4; ++i) {
        const int r = rb + mi * 16 + g * 4 + i;
        const int cI = cb + ni * 16 + lr;
        if (Cf) Cf[(size_t)r * N + cI] = acc[mi][ni][i];
        else    Cb[(size_t)r * N + cI] = f2bf(acc[mi][ni][i]);
      }
}

// ---------------- causal flash attention, per (b,head) -----------------------
// grid (32 bh, 16 q-tiles heavy-first); 4 waves x 32 q-rows. KV tile 64.
// LDS = 40KB (Ps aliases Ks, dead after QK^T) -> 3 blocks/CU at VGPR<=170.
// NO min-occupancy launch bound (r6 lesson: forcing it caused an 84-VGPR spill).
__global__ __launch_bounds__(256) void attn_k(const u16* __restrict__ q, const u16* __restrict__ kvb,
                                              const u16* __restrict__ kpe, u16* __restrict__ ao) {
  __shared__ __attribute__((aligned(16))) u16 Ks[64 * 192];   // also holds Ps after QK
  __shared__ __attribute__((aligned(16))) u16 Vt[128 * 64];

  const float SCALE = 0.07216878364870323f;  // 192^-0.5
  const int bh = blockIdx.x;
  const int b = bh >> 4, h = bh & 15;
  const int j = 15 - blockIdx.y;             // heavy q-tiles dispatch first
  const int tid = threadIdx.x, w = tid >> 6, lane = tid & 63;
  const int lr = lane & 15, g = lane >> 4;

  const int q0 = j * 128;
  const int qrb = q0 + w * 32;
  u16* Psw = &Ks[w * 2304];                  // per-wave 32x72 slice inside Ks

  bf16x8 qf[2][6];
#pragma unroll
  for (int m = 0; m < 2; ++m)
#pragma unroll
    for (int kd = 0; kd < 6; ++kd)
      qf[m][kd] = *(const bf16x8*)(q + (size_t)(b * 2048 + qrb + m * 16 + lr) * 3072 +
                                   h * 192 + kd * 32 + g * 8);

  float mrow[2][4], lrow[2][4];
  f32x4 o[2][8] = {};
#pragma unroll
  for (int m = 0; m < 2; ++m)
#pragma unroll
    for (int i = 0; i < 4; ++i) { mrow[m][i] = -1e30f; lrow[m][i] = 0.f; }

  const int nt = (q0 >> 6) + 2;
  for (int t = 0; t < nt; ++t) {
    const int k0 = t * 64;
    // stage K tile (64 x 192), swizzled: LDS chunk (row, cl) holds global chunk cl^(row&7)
#pragma unroll
    for (int i = 0; i < 6; ++i) {
      const int c = i * 256 + tid;           // 0..1535
      const int row = c / 24, cl = c - row * 24;
      const int cg = cl ^ (row & 7);
      const u16* src = (cg < 16)
        ? (kvb + (size_t)(b * 2048 + k0 + row) * 4096 + h * 256 + cg * 8)
        : (kpe + (size_t)(b * 2048 + k0 + row) * 64 + (cg - 16) * 8);
      GLOAD16(src, &Ks[c * 8]);
    }
    // stage V transposed, swizzled; 4 k-rows packed per ds_write_b64
    {
      const int kq = tid >> 4;               // 0..15, k base = kq*4
      const int vc = (tid & 15) << 3;        // 0..120
      u16x8 vv[4];
#pragma unroll
      for (int r = 0; r < 4; ++r)
        vv[r] = *(const u16x8*)(kvb + (size_t)(b * 2048 + k0 + kq * 4 + r) * 4096 + h * 256 + 128 + vc);
#pragma unroll
      for (int e = 0; e < 8; ++e) {
        const int v = vc + e;
        const int cx = (kq >> 1) ^ (v & 7) ^ ((v >> 3) & 7);
        u16x4 tq = {vv[0][e], vv[1][e], vv[2][e], vv[3][e]};
        *(u16x4*)(&Vt[v * 64 + cx * 8 + (kq & 1) * 4]) = tq;
      }
    }
    __syncthreads();

    const bool active = (k0 <= qrb + 31);    // wave-uniform
    f32x4 sAcc[2][4] = {};
    if (active) {
      // S = Q K^T (32 rows x 64 keys per wave)
#pragma unroll
      for (int nf = 0; nf < 4; ++nf) {
        const int rr = nf * 16 + lr;
#pragma unroll
        for (int kd = 0; kd < 6; ++kd) {
          const int ch = (kd * 4 + g) ^ (rr & 7);
          const bf16x8 kf = *(const bf16x8*)(&Ks[rr * 192 + ch * 8]);
#pragma unroll
          for (int m = 0; m < 2; ++m)
            sAcc[m][nf] = __builtin_amdgcn_mfma_f32_16x16x32_bf16(qf[m][kd], kf, sAcc[m][nf], 0, 0, 0);
        }
      }
    }
    __syncthreads();                         // all Ks reads done; Ps may overwrite

    if (active) {
      // online softmax over 64 keys
#pragma unroll
      for (int m = 0; m < 2; ++m) {
        float sv[4][4];
#pragma unroll
        for (int nf = 0; nf < 4; ++nf)
#pragma unroll
          for (int i = 0; i < 4; ++i) {
            const int qrow = qrb + m * 16 + g * 4 + i;
            const int kcol = k0 + nf * 16 + lr;
            const float vS = sAcc[m][nf][i] * SCALE;
            sv[nf][i] = (kcol > qrow) ? -1e30f : vS;
          }
        float fac[4], mn[4];
#pragma unroll
        for (int i = 0; i < 4; ++i) {
          float rm = fmaxf(fmaxf(sv[0][i], sv[1][i]), fmaxf(sv[2][i], sv[3][i]));
          rm = fmaxf(rm, __shfl_xor(rm, 1));
          rm = fmaxf(rm, __shfl_xor(rm, 2));
          rm = fmaxf(rm, __shfl_xor(rm, 4));
          rm = fmaxf(rm, __shfl_xor(rm, 8));
          mn[i] = fmaxf(mrow[m][i], rm);
          fac[i] = __expf(mrow[m][i] - mn[i]);
          mrow[m][i] = mn[i];
        }
#pragma unroll
        for (int i = 0; i < 4; ++i) {
          float rsum = 0.f;
#pragma unroll
          for (int nf = 0; nf < 4; ++nf) { sv[nf][i] = __expf(sv[nf][i] - mn[i]); rsum += sv[nf][i]; }
          rsum += __shfl_xor(rsum, 1);
          rsum += __shfl_xor(rsum, 2);
          rsum += __shfl_xor(rsum, 4);
          rsum += __shfl_xor(rsum, 8);
          lrow[m][i] = lrow[m][i] * fac[i] + rsum;
        }
#pragma unroll
        for (int nv = 0; nv < 8; ++nv)
#pragma unroll
          for (int i = 0; i < 4; ++i) o[m][nv][i] *= fac[i];
#pragma unroll
        for (int nf = 0; nf < 4; ++nf)
#pragma unroll
          for (int i = 0; i < 4; ++i)
            Psw[(m * 16 + g * 4 + i) * 72 + nf * 16 + lr] = f2bf(sv[nf][i]);
      }
      asm volatile("s_waitcnt lgkmcnt(0)" ::: "memory");

      // O += P V  (two K=32 sub-steps)
#pragma unroll
      for (int kc = 0; kc < 2; ++kc) {
        bf16x8 vfr[8];
#pragma unroll
        for (int nv = 0; nv < 8; ++nv) {
          const int v = nv * 16 + lr;
          const int cx = (kc * 4 + g) ^ (v & 7) ^ ((v >> 3) & 7);
          vfr[nv] = *(const bf16x8*)(&Vt[v * 64 + cx * 8]);
        }
#pragma unroll
        for (int m = 0; m < 2; ++m) {
          const bf16x8 pf = *(const bf16x8*)(&Psw[(m * 16 + lr) * 72 + kc * 32 + g * 8]);
#pragma unroll
          for (int nv = 0; nv < 8; ++nv)
            o[m][nv] = __builtin_amdgcn_mfma_f32_16x16x32_bf16(pf, vfr[nv], o[m][nv], 0, 0, 0);
        }
      }
    }
    __syncthreads();                         // Ps/Vt reads done before next stage
  }

  // epilogue: normalize and store
#pragma unroll
  for (int m = 0; m < 2; ++m)
#pragma unroll
    for (int i = 0; i < 4; ++i) {
      const float inv = 1.0f / lrow[m][i];
      const size_t tokOff = (size_t)(b * 2048 + qrb + m * 16 + g * 4 + i) * 2048 + h * 128;
#pragma unroll
      for (int nv = 0; nv < 8; ++nv)
        ao[tokOff + nv * 16 + lr] = f2bf(o[m][nv][i] * inv);
    }
}

// -----------------------------------------------------------------------------
extern "C" void kernel_launch(void* const* d_in, const int* in_sizes, int n_in,
                              void* d_out, int out_size, void* d_ws, size_t ws_size,
                              hipStream_t stream) {
  const float* hidden  = (const float*)d_in[0];
  const int*   pos     = (const int*)d_in[1];
  const float* q_a_w   = (const float*)d_in[2];
  const float* q_a_ln  = (const float*)d_in[3];
  const float* q_b_w   = (const float*)d_in[4];
  const float* kv_a_w  = (const float*)d_in[5];
  const float* kv_a_ln = (const float*)d_in[6];
  const float* kv_b_w  = (const float*)d_in[7];
  const float* o_w     = (const float*)d_in[8];
  float* out = (float*)d_out;

  char* ws = (char*)d_ws;
  u16* hb  = (u16*)(ws + 0L);          // 4096x2048
  u16* w1  = (u16*)(ws + 16777216L);   // 1536x2048
  u16* w2  = (u16*)(ws + 23068672L);   // 3072x1536
  u16* w3  = (u16*)(ws + 32505856L);   // 640x2048 (padded)
  u16* w4  = (u16*)(ws + 35127296L);   // 4096x512
  u16* w5  = (u16*)(ws + 39321600L);   // 2048x2048
  u16* qa  = (u16*)(ws + 47710208L);   // 4096x1536
  u16* qb  = (u16*)(ws + 60293120L);   // 4096x3072
  u16* kva = (u16*)(ws + 85458944L);   // 4096x640
  u16* ckv = (u16*)(ws + 90701824L);   // 4096x512
  u16* kpe = (u16*)(ws + 94896128L);   // 4096x64
  u16* kvb = (u16*)(ws + 95420416L);   // 4096x4096
  u16* ao  = (u16*)(ws + 128974848L);  // 4096x2048
  if (ws_size < 145752064UL) { fprintf(stderr, "ws too small: %zu\n", ws_size); return; }

  auto cvt = [&](const float* s, u16* d, long sn, long dn) {
    long blocks = (dn / 8 + 255) / 256; if (blocks > 2048) blocks = 2048;
    cvt_pad_k<<<dim3((unsigned)blocks), dim3(256), 0, stream>>>(s, d, sn, dn);
  };
  cvt(hidden, hb, 4096L * 2048, 4096L * 2048);
  cvt(q_a_w,  w1, 1536L * 2048, 1536L * 2048);
  cvt(q_b_w,  w2, 3072L * 1536, 3072L * 1536);
  cvt(kv_a_w, w3, 576L * 2048,  640L * 2048);
  cvt(kv_b_w, w4, 4096L * 512,  4096L * 512);
  cvt(o_w,    w5, 2048L * 2048, 2048L * 2048);

  gemm_bt<<<dim3(12, 32), 256, 0, stream>>>(hb, w1, qa, nullptr, 4096, 1536, 2048);
  rms_k<<<4096, 256, 0, stream>>>(qa, qa, q_a_ln, 1536, 1536, 1536);
  gemm_bt<<<dim3(24, 32), 256, 0, stream>>>(qa, w2, qb, nullptr, 4096, 3072, 1536);
  gemm_bt<<<dim3(5, 32), 256, 0, stream>>>(hb, w3, kva, nullptr, 4096, 640, 2048);
  rms_k<<<4096, 256, 0, stream>>>(kva, ckv, kv_a_ln, 640, 512, 512);
  rope_k<<<4096, 256, 0, stream>>>(qb, kva, kpe, pos);
  gemm_bt<<<dim3(32, 32), 256, 0, stream>>>(ckv, w4, kvb, nullptr, 4096, 4096, 512);
  attn_k<<<dim3(32, 16), 256, 0, stream>>>(qb, kvb, kpe, ao);
  gemm_bt<<<dim3(16, 32), 256, 0, stream>>>(ao, w5, nullptr, out, 4096, 2048, 2048);
}